// Round 1
// baseline (1041.041 us; speedup 1.0000x reference)
//
#include <hip/hip_runtime.h>

// Problem constants (fixed by the reference):
//   state_sequence [B=16, S=128, H=128, W=128] f32; N=32 objects; D=128.
//   T = 127; off-diagonal pairs = 992; out = [1024 cm] ++ [127*992*3 preds].
#define HWC 16384   // H*W
#define NFRM 128    // S
#define NPAIR 992
#define TSTEPS 127

// ---------------- k_scan: the 134 MB streaming reduction ----------------
// fin[t] bits 0..31 = presence mask of frame t; bit32 = has0; bit33 = has1.
__device__ __forceinline__ void step_fn(float2 a, float2 b, int t,
                                        unsigned long long* __restrict__ fin) {
  int ax = (int)a.x, ay = (int)a.y;
  int bx = (int)b.x, by = (int)b.y;
  unsigned m = (1u << (ax & 31)) | (1u << (ay & 31));
  bool h0 = (ax == bx) || (ay == by);   // some cell unchanged
  bool h1 = (ax != bx) || (ay != by);   // some cell changed
#pragma unroll
  for (int o = 32; o; o >>= 1) m |= __shfl_xor(m, o);
  unsigned long long v = m;
  if (__any(h0 ? 1 : 0)) v |= (1ull << 32);
  if (__any(h1 ? 1 : 0)) v |= (1ull << 33);
  if ((threadIdx.x & 63) == 0) atomicOr(&fin[t], v);  // fire-and-forget
}

__global__ __launch_bounds__(256) void k_scan(const float* __restrict__ st,
                                              unsigned long long* __restrict__ fin) {
  int gid = blockIdx.x * 256 + threadIdx.x;     // 131072 threads total
  int b   = gid >> 13;                          // 8192 float2 columns per batch
  int hw2 = gid & 8191;
  const float2* p2 = (const float2*)st;
  size_t base = ((size_t)b * NFRM) * (HWC / 2) + hw2;  // frame f at base + f*8192

  float2 prev = p2[base];                       // frame 0
  // 15 chunks of 8 frames (1..120) -> steps t=0..119; 8 loads in flight.
  for (int c = 0; c < 15; ++c) {
    int f = 1 + c * 8;
    float2 n[8];
#pragma unroll
    for (int u = 0; u < 8; ++u) n[u] = p2[base + (size_t)(f + u) * (HWC / 2)];
    step_fn(prev, n[0], f - 1, fin);
#pragma unroll
    for (int u = 0; u < 7; ++u) step_fn(n[u], n[u + 1], f + u, fin);
    prev = n[7];
  }
  // tail: frames 121..127 -> steps t=120..126
  float2 n[7];
#pragma unroll
  for (int u = 0; u < 7; ++u) n[u] = p2[base + (size_t)(121 + u) * (HWC / 2)];
  step_fn(prev, n[0], 120, fin);
#pragma unroll
  for (int u = 0; u < 6; ++u) step_fn(n[u], n[u + 1], 121 + u, fin);
}

// ---------------- k_cm: sigmoid(causal_matrix + 0.01*present^T @ changed) ----
__global__ __launch_bounds__(1024) void k_cm(const unsigned long long* __restrict__ fin,
                                             const float* __restrict__ cmin,
                                             float* __restrict__ out) {
  __shared__ unsigned long long F[TSTEPS];
  int tid = threadIdx.x;
  if (tid < TSTEPS) F[tid] = fin[tid];
  __syncthreads();
  int i = tid >> 5, j = tid & 31;
  float inc = 0.0f;
  if (j < 2 && i != j) {
    int cnt = 0;
#pragma unroll 1
    for (int t = 0; t < TSTEPS; ++t) {
      unsigned long long f = F[t];
      cnt += (int)(((f >> i) & 1ull) & ((f >> (32 + j)) & 1ull));
    }
    inc = 0.01f * (float)cnt;
  }
  float val = cmin[tid] + inc;
  out[tid] = 1.0f / (1.0f + expf(-val));
}

// ---------------- k_ab: A[i][h] = emb[i]·W1[0:128,h], B[i][h] = emb[i]·W1[128:256,h]
__global__ __launch_bounds__(128) void k_ab(const float* __restrict__ emb,
                                            const float* __restrict__ W1,
                                            float* __restrict__ AB) {
  int blk = blockIdx.x;            // 0..63 ; sel = blk/32, i = blk%32
  int sel = blk >> 5, i = blk & 31;
  int h = threadIdx.x;
  __shared__ float e[128];
  e[h] = emb[i * 128 + h];
  __syncthreads();
  float acc = 0.0f;
  const float* w = W1 + (size_t)sel * 128 * 128 + h;   // row sel*128+k, col h
#pragma unroll 8
  for (int k = 0; k < 128; ++k) acc += e[k] * w[k * 128];
  AB[blk * 128 + h] = acc;         // AB[sel*32+i][h]
}

// ---------------- k_pairs: per off-diagonal pair, mech + broadcast preds ----
__global__ __launch_bounds__(128) void k_pairs(const float* __restrict__ AB,
                                               const float* __restrict__ b1,
                                               const float* __restrict__ W2,
                                               const float* __restrict__ b2,
                                               float* __restrict__ outp) {
  int p = blockIdx.x;              // 0..991, i-major off-diagonal index
  int i = p / 31, r = p - i * 31;
  int j = r + (r >= i ? 1 : 0);
  int h = threadIdx.x;

  float hid = AB[i * 128 + h] + AB[(32 + j) * 128 + h] + b1[h];
  hid = fmaxf(hid, 0.0f);
  float m0 = hid * W2[h * 3 + 0];
  float m1 = hid * W2[h * 3 + 1];
  float m2 = hid * W2[h * 3 + 2];
#pragma unroll
  for (int o = 32; o; o >>= 1) {
    m0 += __shfl_xor(m0, o);
    m1 += __shfl_xor(m1, o);
    m2 += __shfl_xor(m2, o);
  }
  __shared__ float s[2][3];
  if ((h & 63) == 0) { int w = h >> 6; s[w][0] = m0; s[w][1] = m1; s[w][2] = m2; }
  __syncthreads();
  float mech0 = s[0][0] + s[1][0] + b2[0];
  float mech1 = s[0][1] + s[1][1] + b2[1];
  float mech2 = s[0][2] + s[1][2] + b2[2];
  // preds[t*992 + p][0][c] = mech[c] for all t
  for (int idx = h; idx < TSTEPS * 3; idx += 128) {
    int t = idx / 3, c = idx - t * 3;
    float v = (c == 0) ? mech0 : ((c == 1) ? mech1 : mech2);
    outp[((size_t)t * NPAIR + p) * 3 + c] = v;
  }
}

extern "C" void kernel_launch(void* const* d_in, const int* in_sizes, int n_in,
                              void* d_out, int out_size, void* d_ws, size_t ws_size,
                              hipStream_t stream) {
  const float* st   = (const float*)d_in[0];   // state_sequence [16,128,128,128]
  const float* emb  = (const float*)d_in[1];   // [32,128]
  const float* W1   = (const float*)d_in[2];   // [256,128]
  const float* b1   = (const float*)d_in[3];   // [128]
  const float* W2   = (const float*)d_in[4];   // [128,3]
  const float* b2   = (const float*)d_in[5];   // [3]
  const float* cmin = (const float*)d_in[6];   // [32,32]
  float* out = (float*)d_out;                  // [1024 cm] ++ [127*992*3 preds]

  unsigned long long* fin = (unsigned long long*)d_ws;         // 127 * u64
  float* AB = (float*)((char*)d_ws + 1024);                    // 64*128 f32

  hipMemsetAsync(fin, 0, TSTEPS * sizeof(unsigned long long), stream);
  hipLaunchKernelGGL(k_ab,    dim3(64),    dim3(128),  0, stream, emb, W1, AB);
  hipLaunchKernelGGL(k_scan,  dim3(512),   dim3(256),  0, stream, st, fin);
  hipLaunchKernelGGL(k_cm,    dim3(1),     dim3(1024), 0, stream, fin, cmin, out);
  hipLaunchKernelGGL(k_pairs, dim3(NPAIR), dim3(128),  0, stream, AB, b1, W2, b2, out + 1024);
}

// Round 2
// 224.160 us; speedup vs baseline: 4.6442x; 4.6442x over previous
//
#include <hip/hip_runtime.h>

// Problem constants (fixed by the reference):
//   state_sequence [B=16, S=128, H=128, W=128] f32; N=32 objects; D=128.
//   T = 127; off-diagonal pairs = 992; out = [1024 cm] ++ [127*992*3 preds].
#define HWC 16384        // H*W
#define NFRM 128         // S
#define NPAIR 992
#define TSTEPS 127
#define SCAN_BLOCKS 256  // 256 blocks x 512 threads = 131072 threads (one f32x2 column each)
#define PRED_N (TSTEPS * NPAIR * 3)  // 377952

// ---------------- k_scan: the 134 MB streaming reduction ----------------
// Per wave, per t: presence mask of frame t (bits 0..31), has0 (bit 32),
// has1 (bit 33). Wave-reduced via shfl, written to the wave's OWN LDS slot
// (no atomics anywhere in the hot loop), block-combined at the end into
// partial[block][t] (coalesced 8B stores).
__device__ __forceinline__ void step_fn(float2 a, float2 b, int t, int wv,
                                        unsigned long long (*part)[TSTEPS]) {
  int ax = (int)a.x, ay = (int)a.y;
  int bx = (int)b.x, by = (int)b.y;
  unsigned m = (1u << (ax & 31)) | (1u << (ay & 31));
  bool h0 = (ax == bx) || (ay == by);   // some cell unchanged
  bool h1 = (ax != bx) || (ay != by);   // some cell changed
#pragma unroll
  for (int o = 32; o; o >>= 1) m |= __shfl_xor(m, o);
  unsigned long long v = m;
  if (__any(h0 ? 1 : 0)) v |= (1ull << 32);
  if (__any(h1 ? 1 : 0)) v |= (1ull << 33);
  if ((threadIdx.x & 63) == 0) part[wv][t] = v;   // plain LDS write
}

__global__ __launch_bounds__(512) void k_scan(const float* __restrict__ st,
                                              unsigned long long* __restrict__ partial) {
  __shared__ unsigned long long part[8][TSTEPS];
  int gid = blockIdx.x * 512 + threadIdx.x;     // 131072 threads total
  int wv  = threadIdx.x >> 6;
  int b   = gid >> 13;                          // 8192 float2 columns per batch
  int hw2 = gid & 8191;
  const float2* p2 = (const float2*)st;
  size_t base = ((size_t)b * NFRM) * (HWC / 2) + hw2;  // frame f at base + f*8192

  float2 prev = p2[base];                       // frame 0
  // 15 chunks of 8 frames (1..120) -> steps t=0..119; 8 loads in flight.
  for (int c = 0; c < 15; ++c) {
    int f = 1 + c * 8;
    float2 n[8];
#pragma unroll
    for (int u = 0; u < 8; ++u) n[u] = p2[base + (size_t)(f + u) * (HWC / 2)];
    step_fn(prev, n[0], f - 1, wv, part);
#pragma unroll
    for (int u = 0; u < 7; ++u) step_fn(n[u], n[u + 1], f + u, wv, part);
    prev = n[7];
  }
  // tail: frames 121..127 -> steps t=120..126
  float2 n[7];
#pragma unroll
  for (int u = 0; u < 7; ++u) n[u] = p2[base + (size_t)(121 + u) * (HWC / 2)];
  step_fn(prev, n[0], 120, wv, part);
#pragma unroll
  for (int u = 0; u < 6; ++u) step_fn(n[u], n[u + 1], 121 + u, wv, part);

  __syncthreads();
  int t = threadIdx.x;
  if (t < TSTEPS) {
    unsigned long long v = part[0][t] | part[1][t] | part[2][t] | part[3][t] |
                           part[4][t] | part[5][t] | part[6][t] | part[7][t];
    partial[(size_t)blockIdx.x * TSTEPS + t] = v;   // coalesced per-block row
  }
}

// ---------------- k_cm: reduce partials, then sigmoid(cm + inc) ----------
__global__ __launch_bounds__(1024) void k_cm(const unsigned long long* __restrict__ partial,
                                             const float* __restrict__ cmin,
                                             float* __restrict__ out) {
  __shared__ unsigned long long G[TSTEPS][9];   // 9 = pad for bank spread
  __shared__ unsigned long long F[TSTEPS];
  int tid = threadIdx.x;
  // stage 1: 1016 threads, (t, chunk c of 8) each OR 32 blocks' partials
  if (tid < TSTEPS * 8) {
    int t = tid >> 3, c = tid & 7;
    unsigned long long v = 0;
#pragma unroll 4
    for (int b = c; b < SCAN_BLOCKS; b += 8) v |= partial[(size_t)b * TSTEPS + t];
    G[t][c] = v;
  }
  __syncthreads();
  if (tid < TSTEPS) {
    F[tid] = G[tid][0] | G[tid][1] | G[tid][2] | G[tid][3] |
             G[tid][4] | G[tid][5] | G[tid][6] | G[tid][7];
  }
  __syncthreads();
  int i = tid >> 5, j = tid & 31;
  float inc = 0.0f;
  if (j < 2 && i != j) {
    int cnt = 0;
#pragma unroll 1
    for (int t = 0; t < TSTEPS; ++t) {
      unsigned long long f = F[t];
      cnt += (int)(((f >> i) & 1ull) & ((f >> (32 + j)) & 1ull));
    }
    inc = 0.01f * (float)cnt;
  }
  float val = cmin[tid] + inc;
  out[tid] = 1.0f / (1.0f + expf(-val));
}

// ---------------- k_ab: A[i][h] = emb[i]·W1[0:128,h], B[i][h] = emb[i]·W1[128:256,h]
// W1 half staged through LDS with coalesced float4 loads (kills stride-512B
// column reads).
__global__ __launch_bounds__(128) void k_ab(const float* __restrict__ emb,
                                            const float* __restrict__ W1,
                                            float* __restrict__ AB) {
  int blk = blockIdx.x;            // 0..63 ; sel = blk/32, i = blk%32
  int sel = blk >> 5, i = blk & 31;
  int h = threadIdx.x;
  __shared__ float e[128];
  __shared__ float Wl[128 * 128];  // 64 KB: W1 rows sel*128 .. sel*128+127
  e[h] = emb[i * 128 + h];
  const float4* src = (const float4*)(W1 + (size_t)sel * 128 * 128);
  float4* dst = (float4*)Wl;
#pragma unroll
  for (int k = 0; k < 32; ++k) dst[k * 128 + h] = src[k * 128 + h];
  __syncthreads();
  float acc = 0.0f;
#pragma unroll 8
  for (int k = 0; k < 128; ++k) acc += e[k] * Wl[k * 128 + h];
  AB[blk * 128 + h] = acc;         // AB[sel*32+i][h]
}

// ---------------- k_pairs: per off-diagonal pair, mech[p][3] ----------------
__global__ __launch_bounds__(128) void k_pairs(const float* __restrict__ AB,
                                               const float* __restrict__ b1,
                                               const float* __restrict__ W2,
                                               const float* __restrict__ b2,
                                               float* __restrict__ mech) {
  int p = blockIdx.x;              // 0..991, i-major off-diagonal index
  int i = p / 31, r = p - i * 31;
  int j = r + (r >= i ? 1 : 0);
  int h = threadIdx.x;

  float hid = AB[i * 128 + h] + AB[(32 + j) * 128 + h] + b1[h];
  hid = fmaxf(hid, 0.0f);
  float m0 = hid * W2[h * 3 + 0];
  float m1 = hid * W2[h * 3 + 1];
  float m2 = hid * W2[h * 3 + 2];
#pragma unroll
  for (int o = 32; o; o >>= 1) {
    m0 += __shfl_xor(m0, o);
    m1 += __shfl_xor(m1, o);
    m2 += __shfl_xor(m2, o);
  }
  __shared__ float s[2][3];
  if ((h & 63) == 0) { int w = h >> 6; s[w][0] = m0; s[w][1] = m1; s[w][2] = m2; }
  __syncthreads();
  if (h < 3) {
    float v = s[0][h] + s[1][h] + b2[h];
    mech[p * 3 + h] = v;
  }
}

// ---------------- k_preds: broadcast mech over t with coalesced writes ------
__global__ __launch_bounds__(256) void k_preds(const float* __restrict__ mech,
                                               float* __restrict__ outp) {
  int idx = blockIdx.x * 256 + threadIdx.x;
  if (idx < PRED_N) {
    int q = idx / 3;               // t*992 + p
    int c = idx - q * 3;
    int p = q % NPAIR;
    outp[idx] = mech[p * 3 + c];   // consecutive idx -> consecutive outp
  }
}

extern "C" void kernel_launch(void* const* d_in, const int* in_sizes, int n_in,
                              void* d_out, int out_size, void* d_ws, size_t ws_size,
                              hipStream_t stream) {
  const float* st   = (const float*)d_in[0];   // state_sequence [16,128,128,128]
  const float* emb  = (const float*)d_in[1];   // [32,128]
  const float* W1   = (const float*)d_in[2];   // [256,128]
  const float* b1   = (const float*)d_in[3];   // [128]
  const float* W2   = (const float*)d_in[4];   // [128,3]
  const float* b2   = (const float*)d_in[5];   // [3]
  const float* cmin = (const float*)d_in[6];   // [32,32]
  float* out = (float*)d_out;                  // [1024 cm] ++ [127*992*3 preds]

  // Workspace layout (all fully written before read; no init needed):
  unsigned long long* partial = (unsigned long long*)d_ws;           // 256*127*8 = 260 KB
  float* AB   = (float*)((char*)d_ws + SCAN_BLOCKS * TSTEPS * 8);    // 64*128*4 = 32 KB
  float* mech = AB + 64 * 128;                                       // 992*3*4 ≈ 12 KB

  hipLaunchKernelGGL(k_ab,    dim3(64),          dim3(128), 0, stream, emb, W1, AB);
  hipLaunchKernelGGL(k_scan,  dim3(SCAN_BLOCKS), dim3(512), 0, stream, st, partial);
  hipLaunchKernelGGL(k_cm,    dim3(1),           dim3(1024), 0, stream, partial, cmin, out);
  hipLaunchKernelGGL(k_pairs, dim3(NPAIR),       dim3(128), 0, stream, AB, b1, W2, b2, mech);
  hipLaunchKernelGGL(k_preds, dim3((PRED_N + 255) / 256), dim3(256), 0, stream,
                     mech, out + 1024);
}